// Round 4
// baseline (48.018 us; speedup 1.0000x reference)
//
#include <hip/hip_runtime.h>
#include <hip/hip_bf16.h>

// loss_separation: X[n, b*2+c] = keypoints[b, n, c], N=8192 rows, K=128 cols.
// loss = sum_{i != j} exp(-0.4 * ||X_i - X_j||)
// Pipeline:
//   1. prep:   build bf16 X in MFMA-fragment-swizzled layout + fp32 row norms
//   2. pairs:  upper-tri 128x128 tiles; stage A/B tiles to LDS via
//              global_load_lds(16B); MFMA bf16 dots; sqrt+exp2 epilogue
//   3. reduce: sum per-tile partials -> d_out[0]

#define N_KP   8192
#define KDIM   128          // B*C = 64*2
#define NT     64           // number of 128-row tiles
#define NTILES (NT * (NT + 1) / 2)   // 2080 upper-tri tiles
#define COEF2  (-0.57707801635558535f)   // -0.4 * log2(e)

typedef __attribute__((ext_vector_type(8))) short bf16x8;
typedef __attribute__((ext_vector_type(4))) float f32x4;

// Swizzled X layout (ushort units): fragment f = (rowblk16*4 + kk) holds the
// MFMA A/B fragment for rows [rowblk16*16, +16), k in [kk*32, +32):
//   Xs[f*512 + slot*8 + e], slot = (lane>>4)*16 + (lane&15)
//   = X[rowblk16*16 + (lane&15)][kk*32 + (lane>>4)*8 + e]
// One fragment = 1 KB, contiguous. A 128-row tile t = fragments [t*32, t*32+32).

__device__ __forceinline__ unsigned short f2bf(float f) {
    // round-to-nearest-even bf16 (inputs are uniform [0,1), no NaN/Inf)
    unsigned int u = __builtin_bit_cast(unsigned int, f);
    unsigned int r = (u + 0x7FFFu + ((u >> 16) & 1u)) >> 16;
    return (unsigned short)r;
}

__device__ __forceinline__ float bf2f(unsigned short u) {
    unsigned int x = ((unsigned int)u) << 16;
    return __builtin_bit_cast(float, x);
}

__device__ __forceinline__ void gload_lds16(const void* g, void* l) {
    __builtin_amdgcn_global_load_lds(
        (const __attribute__((address_space(1))) unsigned int*)g,
        (__attribute__((address_space(3))) unsigned int*)l, 16, 0, 0);
}

// 256 blocks x 256 threads; block handles 32 keypoints, thread handles 8 b's.
// part p = tid>>5 (b-range), idx = tid&31 (n within block). Loads: 2x256B
// contiguous segments per wave instruction. sq reduced via LDS.
__global__ __launch_bounds__(256) void prep_kernel(
        const float* __restrict__ in, unsigned short* __restrict__ Xbf,
        float* __restrict__ sq) {
    int tid = threadIdx.x;
    int p = tid >> 5, idx = tid & 31;
    int n = blockIdx.x * 32 + idx;
    int t16 = n >> 4, l16 = n & 15;
    unsigned int* dst = (unsigned int*)Xbf;
    float s = 0.0f;
    #pragma unroll
    for (int q = 0; q < 8; ++q) {
        int b = p * 8 + q;
        float2 v = *(const float2*)(in + (size_t)b * (N_KP * 2) + n * 2);
        unsigned short h0 = f2bf(v.x);
        unsigned short h1 = f2bf(v.y);
        float f0 = bf2f(h0), f1 = bf2f(h1);
        s = fmaf(f0, f0, s);
        s = fmaf(f1, f1, s);
        // k = 2b (+c): kk = b>>4, lhi = (b>>2)&3, e = (b&3)*2
        unsigned int off_us = (((unsigned)(t16 * 4 + (b >> 4)) * 64
                                + ((b >> 2) & 3) * 16 + l16) << 3) + ((b & 3) << 1);
        dst[off_us >> 1] = ((unsigned int)h1 << 16) | h0;
    }
    __shared__ float wsq[256];
    wsq[tid] = s;
    __syncthreads();
    if (tid < 32) {
        float t = 0.0f;
        #pragma unroll
        for (int pp = 0; pp < 8; ++pp) t += wsq[pp * 32 + tid];
        sq[blockIdx.x * 32 + tid] = t;
    }
}

// Upper-triangular tile kernel. Block = 256 threads = 4 waves in a 2x2 grid.
// Stage: 64 x 1KB fragment chunks (A tile 32KB + B tile 32KB) into LDS via
// global_load_lds width-16 (16 instrs/wave). Then each wave computes a 64x64
// subtile: 4x4 fragments x 4 K-steps of mfma_f32_16x16x32_bf16 fed by
// contiguous ds_read_b128 (conflict-free), plus sqrt+exp2 epilogue.
__global__ __launch_bounds__(256) void pair_kernel(
        const unsigned short* __restrict__ Xbf, const float* __restrict__ sq,
        float* __restrict__ partials) {
    int bid = blockIdx.x;
    // decode (ti, tj), ti <= tj: off(t) = t*(129-t)/2 tiles precede row t.
    int ti = (int)((129.0f - sqrtf(129.0f * 129.0f - 8.0f * (float)bid)) * 0.5f);
    while (ti > 0 && ti * (129 - ti) / 2 > bid) --ti;
    while ((ti + 1) * (129 - (ti + 1)) / 2 <= bid) ++ti;
    int tj = ti + (bid - ti * (129 - ti) / 2);

    int wid  = threadIdx.x >> 6;
    int lane = threadIdx.x & 63;
    int wr = wid >> 1, wc = wid & 1;
    int l16 = lane & 15, lhi = lane >> 4;

    __shared__ __align__(16) unsigned short tileLDS[64 * 512];  // 64 KB

    // stage: chunk c in [wid*16, wid*16+16); c<32 -> A frag ti*32+c,
    // c>=32 -> B frag tj*32+(c-32). src per-lane = frag*1024 + lane*16 bytes.
    const char* src_base = (const char*)Xbf;
    #pragma unroll
    for (int c0 = 0; c0 < 16; ++c0) {
        int c = wid * 16 + c0;
        int fidx = (c < 32) ? (ti * 32 + c) : (tj * 32 + (c - 32));
        gload_lds16(src_base + (size_t)fidx * 1024 + lane * 16,
                    (char*)tileLDS + (size_t)c * 1024);
    }
    __syncthreads();

    const bf16x8* L = (const bf16x8*)tileLDS;   // local fragment f at L[f*64 + lane]
    // local fragment index = rowblk16_local*4 + kk; A tiles occupy rowblk16
    // 0..7 (frags 0..31), B tiles occupy rowblk16 8..15 (frags 32..63).
    int abase = (wr * 4) * 4;        // A: rowblk16_local = wr*4 + m
    int bbase = (8 + wc * 4) * 4;    // B: rowblk16_local = 8 + wc*4 + n

    f32x4 acc[4][4] = {};
    #pragma unroll
    for (int kk = 0; kk < 4; ++kk) {
        bf16x8 a[4], b[4];
        #pragma unroll
        for (int m = 0; m < 4; ++m)
            a[m] = L[(abase + m * 4 + kk) * 64 + lane];
        #pragma unroll
        for (int n = 0; n < 4; ++n)
            b[n] = L[(bbase + n * 4 + kk) * 64 + lane];
        #pragma unroll
        for (int m = 0; m < 4; ++m)
            #pragma unroll
            for (int n = 0; n < 4; ++n)
                acc[m][n] = __builtin_amdgcn_mfma_f32_16x16x32_bf16(
                    a[m], b[n], acc[m][n], 0, 0, 0);
    }

    int ibase = ti * 128 + wr * 64;
    int jbase = tj * 128 + wc * 64;

    // epilogue: D[row][col], row = lhi*4 + r (+m*16), col = l16 (+n*16)
    float si[4][4];
    #pragma unroll
    for (int m = 0; m < 4; ++m)
        #pragma unroll
        for (int r = 0; r < 4; ++r)
            si[m][r] = sq[ibase + m * 16 + lhi * 4 + r];
    float sqj[4];
    #pragma unroll
    for (int n = 0; n < 4; ++n) sqj[n] = sq[jbase + n * 16 + l16];

    float p[4] = {0.0f, 0.0f, 0.0f, 0.0f};
    #pragma unroll
    for (int m = 0; m < 4; ++m) {
        #pragma unroll
        for (int n = 0; n < 4; ++n) {
            #pragma unroll
            for (int r = 0; r < 4; ++r) {
                float d2 = fmaf(-2.0f, acc[m][n][r], si[m][r] + sqj[n]);
                float d = sqrtf(fabsf(d2));       // abs: free input modifier
                p[r] += exp2f(COEF2 * d);         // v_exp_f32
            }
        }
    }
    float partial = (p[0] + p[1]) + (p[2] + p[3]);

    #pragma unroll
    for (int m = 32; m; m >>= 1) partial += __shfl_xor(partial, m, 64);
    __shared__ float wsum[4];
    if (lane == 0) wsum[wid] = partial;
    __syncthreads();
    if (threadIdx.x == 0) {
        float v = (wsum[0] + wsum[1]) + (wsum[2] + wsum[3]);
        // diagonal tiles: remove the 128 i==j terms (each ~= exp(0) = 1).
        // off-diagonal tiles: mirror tile (tj, ti) not computed -> double.
        if (ti == tj) v -= 128.0f; else v *= 2.0f;
        partials[bid] = v;
    }
}

__global__ __launch_bounds__(256) void reduce_kernel(
        const float* __restrict__ partials, float* __restrict__ out) {
    float s = 0.0f;
    for (int i = threadIdx.x; i < NTILES; i += 256) s += partials[i];
    #pragma unroll
    for (int m = 32; m; m >>= 1) s += __shfl_xor(s, m, 64);
    __shared__ float wsum[4];
    int wid = threadIdx.x >> 6, lane = threadIdx.x & 63;
    if (lane == 0) wsum[wid] = s;
    __syncthreads();
    if (threadIdx.x == 0) out[0] = (wsum[0] + wsum[1]) + (wsum[2] + wsum[3]);
}

extern "C" void kernel_launch(void* const* d_in, const int* in_sizes, int n_in,
                              void* d_out, int out_size, void* d_ws, size_t ws_size,
                              hipStream_t stream) {
    const float* in = (const float*)d_in[0];
    float* out = (float*)d_out;

    // workspace layout: Xs (2 MB) | sq (32 KB) | partials (NTILES*4 B)
    unsigned short* Xbf = (unsigned short*)d_ws;
    float* sq = (float*)((char*)d_ws + (size_t)N_KP * KDIM * 2);
    float* partials = (float*)((char*)d_ws + (size_t)N_KP * KDIM * 2
                               + (size_t)N_KP * 4);

    prep_kernel<<<N_KP / 32, 256, 0, stream>>>(in, Xbf, sq);
    pair_kernel<<<NTILES, 256, 0, stream>>>(Xbf, sq, partials);
    reduce_kernel<<<1, 256, 0, stream>>>(partials, out);
}

// Round 5
// 34.683 us; speedup vs baseline: 1.3845x; 1.3845x over previous
//
#include <hip/hip_runtime.h>
#include <hip/hip_bf16.h>

// loss_separation: X[n, b*2+c] = keypoints[b, n, c], N=8192 rows, K=128 cols.
// loss = sum_{i != j} exp(-0.4 * ||X_i - X_j||)
// Pipeline:
//   1. prep:   build bf16 X in MFMA-fragment-swizzled layout + fp32 row norms
//   2. pairs:  upper-tri 128x128 tiles; stage A/B tiles to LDS via
//              global_load_lds(16B); MFMA bf16 dots; v_sqrt+v_exp epilogue
//   3. reduce: sum per-tile partials -> d_out[0]

#define N_KP   8192
#define KDIM   128          // B*C = 64*2
#define NT     64           // number of 128-row tiles
#define NTILES (NT * (NT + 1) / 2)   // 2080 upper-tri tiles
#define COEF2  (-0.57707801635558535f)   // -0.4 * log2(e)

typedef __attribute__((ext_vector_type(8))) short bf16x8;
typedef __attribute__((ext_vector_type(4))) float f32x4;

// Swizzled X layout (ushort units): fragment f = (rowblk16*4 + kk) holds the
// MFMA A/B fragment for rows [rowblk16*16, +16), k in [kk*32, +32):
//   Xs[f*512 + slot*8 + e], slot = (lane>>4)*16 + (lane&15)
//   = X[rowblk16*16 + (lane&15)][kk*32 + (lane>>4)*8 + e]
// One fragment = 1 KB, contiguous. A 128-row tile t = fragments [t*32, t*32+32).

__device__ __forceinline__ unsigned short f2bf(float f) {
    // round-to-nearest-even bf16 (inputs are uniform [0,1), no NaN/Inf)
    unsigned int u = __builtin_bit_cast(unsigned int, f);
    unsigned int r = (u + 0x7FFFu + ((u >> 16) & 1u)) >> 16;
    return (unsigned short)r;
}

__device__ __forceinline__ float bf2f(unsigned short u) {
    unsigned int x = ((unsigned int)u) << 16;
    return __builtin_bit_cast(float, x);
}

__device__ __forceinline__ void gload_lds16(const void* g, void* l) {
    __builtin_amdgcn_global_load_lds(
        (const __attribute__((address_space(1))) unsigned int*)g,
        (__attribute__((address_space(3))) unsigned int*)l, 16, 0, 0);
}

// 256 blocks x 256 threads; block handles 32 keypoints, thread handles 8 b's.
__global__ __launch_bounds__(256) void prep_kernel(
        const float* __restrict__ in, unsigned short* __restrict__ Xbf,
        float* __restrict__ sq) {
    int tid = threadIdx.x;
    int p = tid >> 5, idx = tid & 31;
    int n = blockIdx.x * 32 + idx;
    int t16 = n >> 4, l16 = n & 15;
    unsigned int* dst = (unsigned int*)Xbf;
    float s = 0.0f;
    #pragma unroll
    for (int q = 0; q < 8; ++q) {
        int b = p * 8 + q;
        float2 v = *(const float2*)(in + (size_t)b * (N_KP * 2) + n * 2);
        unsigned short h0 = f2bf(v.x);
        unsigned short h1 = f2bf(v.y);
        float f0 = bf2f(h0), f1 = bf2f(h1);
        s = fmaf(f0, f0, s);
        s = fmaf(f1, f1, s);
        // k = 2b (+c): kk = b>>4, lhi = (b>>2)&3, e = (b&3)*2
        unsigned int off_us = (((unsigned)(t16 * 4 + (b >> 4)) * 64
                                + ((b >> 2) & 3) * 16 + l16) << 3) + ((b & 3) << 1);
        dst[off_us >> 1] = ((unsigned int)h1 << 16) | h0;
    }
    __shared__ float wsq[256];
    wsq[tid] = s;
    __syncthreads();
    if (tid < 32) {
        float t = 0.0f;
        #pragma unroll
        for (int pp = 0; pp < 8; ++pp) t += wsq[pp * 32 + tid];
        sq[blockIdx.x * 32 + tid] = t;
    }
}

// Upper-triangular tile kernel. Block = 256 threads = 4 waves in a 2x2 grid.
// Stage A (32KB) + B (32KB) tiles into LDS via global_load_lds width-16,
// then 4x4 fragments x 4 K-steps of mfma_f32_16x16x32_bf16 per wave, fed by
// contiguous ds_read_b128. Epilogue: single-instruction v_sqrt_f32 /
// v_exp_f32 (libm sqrtf/exp2f expand to multi-instr IEEE sequences -> 5x
// VALU bloat, measured round 4: VALUBusy 64% at 42us).
__global__ __launch_bounds__(256) void pair_kernel(
        const unsigned short* __restrict__ Xbf, const float* __restrict__ sq,
        float* __restrict__ partials) {
    int bid = blockIdx.x;
    // decode (ti, tj), ti <= tj: off(t) = t*(129-t)/2 tiles precede row t.
    int ti = (int)((129.0f - sqrtf(129.0f * 129.0f - 8.0f * (float)bid)) * 0.5f);
    while (ti > 0 && ti * (129 - ti) / 2 > bid) --ti;
    while ((ti + 1) * (129 - (ti + 1)) / 2 <= bid) ++ti;
    int tj = ti + (bid - ti * (129 - ti) / 2);

    int wid  = threadIdx.x >> 6;
    int lane = threadIdx.x & 63;
    int wr = wid >> 1, wc = wid & 1;
    int l16 = lane & 15, lhi = lane >> 4;

    __shared__ __align__(16) unsigned short tileLDS[64 * 512];  // 64 KB

    // stage: chunk c in [wid*16, wid*16+16); c<32 -> A frag ti*32+c,
    // c>=32 -> B frag tj*32+(c-32). src per-lane = frag*1024 + lane*16 bytes.
    const char* src_base = (const char*)Xbf;
    #pragma unroll
    for (int c0 = 0; c0 < 16; ++c0) {
        int c = wid * 16 + c0;
        int fidx = (c < 32) ? (ti * 32 + c) : (tj * 32 + (c - 32));
        gload_lds16(src_base + (size_t)fidx * 1024 + lane * 16,
                    (char*)tileLDS + (size_t)c * 1024);
    }
    __syncthreads();

    const bf16x8* L = (const bf16x8*)tileLDS;   // local fragment f at L[f*64 + lane]
    // local fragment index = rowblk16_local*4 + kk; A tiles occupy rowblk16
    // 0..7 (frags 0..31), B tiles occupy rowblk16 8..15 (frags 32..63).
    int abase = (wr * 4) * 4;        // A: rowblk16_local = wr*4 + m
    int bbase = (8 + wc * 4) * 4;    // B: rowblk16_local = 8 + wc*4 + n

    f32x4 acc[4][4] = {};
    #pragma unroll
    for (int kk = 0; kk < 4; ++kk) {
        bf16x8 a[4], b[4];
        #pragma unroll
        for (int m = 0; m < 4; ++m)
            a[m] = L[(abase + m * 4 + kk) * 64 + lane];
        #pragma unroll
        for (int n = 0; n < 4; ++n)
            b[n] = L[(bbase + n * 4 + kk) * 64 + lane];
        #pragma unroll
        for (int m = 0; m < 4; ++m)
            #pragma unroll
            for (int n = 0; n < 4; ++n)
                acc[m][n] = __builtin_amdgcn_mfma_f32_16x16x32_bf16(
                    a[m], b[n], acc[m][n], 0, 0, 0);
    }

    int ibase = ti * 128 + wr * 64;
    int jbase = tj * 128 + wc * 64;

    // epilogue: D[row][col], row = lhi*4 + r (+m*16), col = l16 (+n*16)
    float si[4][4];
    #pragma unroll
    for (int m = 0; m < 4; ++m)
        #pragma unroll
        for (int r = 0; r < 4; ++r)
            si[m][r] = sq[ibase + m * 16 + lhi * 4 + r];
    float sqj[4];
    #pragma unroll
    for (int n = 0; n < 4; ++n) sqj[n] = sq[jbase + n * 16 + l16];

    float p[4] = {0.0f, 0.0f, 0.0f, 0.0f};
    #pragma unroll
    for (int m = 0; m < 4; ++m) {
        #pragma unroll
        for (int n = 0; n < 4; ++n) {
            #pragma unroll
            for (int r = 0; r < 4; ++r) {
                float d2 = fmaf(-2.0f, acc[m][n][r], si[m][r] + sqj[n]);
                float d = __builtin_amdgcn_sqrtf(fabsf(d2));  // v_sqrt_f32
                p[r] += __builtin_amdgcn_exp2f(COEF2 * d);    // v_exp_f32
            }
        }
    }
    float partial = (p[0] + p[1]) + (p[2] + p[3]);

    #pragma unroll
    for (int m = 32; m; m >>= 1) partial += __shfl_xor(partial, m, 64);
    __shared__ float wsum[4];
    if (lane == 0) wsum[wid] = partial;
    __syncthreads();
    if (threadIdx.x == 0) {
        float v = (wsum[0] + wsum[1]) + (wsum[2] + wsum[3]);
        // diagonal tiles: remove the 128 i==j terms (each ~= exp(0) = 1).
        // off-diagonal tiles: mirror tile (tj, ti) not computed -> double.
        if (ti == tj) v -= 128.0f; else v *= 2.0f;
        partials[bid] = v;
    }
}

__global__ __launch_bounds__(256) void reduce_kernel(
        const float* __restrict__ partials, float* __restrict__ out) {
    float s = 0.0f;
    for (int i = threadIdx.x; i < NTILES; i += 256) s += partials[i];
    #pragma unroll
    for (int m = 32; m; m >>= 1) s += __shfl_xor(s, m, 64);
    __shared__ float wsum[4];
    int wid = threadIdx.x >> 6, lane = threadIdx.x & 63;
    if (lane == 0) wsum[wid] = s;
    __syncthreads();
    if (threadIdx.x == 0) out[0] = (wsum[0] + wsum[1]) + (wsum[2] + wsum[3]);
}

extern "C" void kernel_launch(void* const* d_in, const int* in_sizes, int n_in,
                              void* d_out, int out_size, void* d_ws, size_t ws_size,
                              hipStream_t stream) {
    const float* in = (const float*)d_in[0];
    float* out = (float*)d_out;

    // workspace layout: Xs (2 MB) | sq (32 KB) | partials (NTILES*4 B)
    unsigned short* Xbf = (unsigned short*)d_ws;
    float* sq = (float*)((char*)d_ws + (size_t)N_KP * KDIM * 2);
    float* partials = (float*)((char*)d_ws + (size_t)N_KP * KDIM * 2
                               + (size_t)N_KP * 4);

    prep_kernel<<<N_KP / 32, 256, 0, stream>>>(in, Xbf, sq);
    pair_kernel<<<NTILES, 256, 0, stream>>>(Xbf, sq, partials);
    reduce_kernel<<<1, 256, 0, stream>>>(partials, out);
}